// Round 1
// baseline (298.186 us; speedup 1.0000x reference)
//
#include <hip/hip_runtime.h>

#define B_DIM 512
#define T_DIM 4096
#define R_DIM 16
// T_DIM = 4096 -> row >> 12 gives batch index

__device__ __forceinline__ float hsum4(float4 v) { return (v.x + v.y) + (v.z + v.w); }

__device__ __forceinline__ float masked_dot(float4 x, float4 m) {
    return ((x.x * m.x + x.y * m.y) + (x.z * m.z + x.w * m.w));
}

__device__ __forceinline__ float masked_sq(float4 x, float4 m, float mean) {
    float dx = x.x - mean, dy = x.y - mean, dz = x.z - mean, dw = x.w - mean;
    return ((dx * dx * m.x + dy * dy * m.y) + (dz * dz * m.z + dw * dw * m.w));
}

// Kernel 1: per-batch n, count of valid batches (n > 1); zero the accumulator.
__global__ __launch_bounds__(B_DIM) void rcl_prep(const float* __restrict__ mask,
                                                  double* __restrict__ acc,
                                                  float* __restrict__ n_multi) {
    __shared__ float red[B_DIM];
    const int b = threadIdx.x;
    const float4* mp = reinterpret_cast<const float4*>(mask) + b * 4;
    float4 m0 = mp[0], m1 = mp[1], m2 = mp[2], m3 = mp[3];
    float n = hsum4(m0) + hsum4(m1) + hsum4(m2) + hsum4(m3);
    red[b] = (n > 1.0f) ? 1.0f : 0.0f;
    __syncthreads();
    for (int s = B_DIM / 2; s > 0; s >>= 1) {
        if (b < s) red[b] += red[b + s];
        __syncthreads();
    }
    if (b == 0) {
        *n_multi = red[0];
        *acc = 0.0;
    }
}

// Kernel 2: one thread per (b, t) row. Accumulate (var_p - var_t)^2 for valid b.
__global__ __launch_bounds__(256) void rcl_main(const float* __restrict__ pred,
                                                const float* __restrict__ targ,
                                                const float* __restrict__ mask,
                                                double* __restrict__ acc) {
    const int row = blockIdx.x * 256 + threadIdx.x;
    const int b = row >> 12;  // row / T_DIM

    const float4* mp = reinterpret_cast<const float4*>(mask) + b * 4;
    float4 m0 = mp[0], m1 = mp[1], m2 = mp[2], m3 = mp[3];
    float n = hsum4(m0) + hsum4(m1) + hsum4(m2) + hsum4(m3);

    float contrib = 0.0f;
    if (n > 1.0f) {  // wave-uniform: all rows of a batch share this predicate
        const float4* pp = reinterpret_cast<const float4*>(pred) + (size_t)row * 4;
        const float4* tp = reinterpret_cast<const float4*>(targ) + (size_t)row * 4;
        float4 p0 = pp[0], p1 = pp[1], p2 = pp[2], p3 = pp[3];
        float4 q0 = tp[0], q1 = tp[1], q2 = tp[2], q3 = tp[3];

        float sp = (masked_dot(p0, m0) + masked_dot(p1, m1)) +
                   (masked_dot(p2, m2) + masked_dot(p3, m3));
        float sq = (masked_dot(q0, m0) + masked_dot(q1, m1)) +
                   (masked_dot(q2, m2) + masked_dot(q3, m3));
        float mean_p = sp / n;  // n_safe == n for n > 1 (n >= 2 since mask is 0/1 counts)
        float mean_q = sq / n;
        float inv_nm1 = 1.0f / (n - 1.0f);
        float vp = ((masked_sq(p0, m0, mean_p) + masked_sq(p1, m1, mean_p)) +
                    (masked_sq(p2, m2, mean_p) + masked_sq(p3, m3, mean_p))) * inv_nm1;
        float vq = ((masked_sq(q0, m0, mean_q) + masked_sq(q1, m1, mean_q)) +
                    (masked_sq(q2, m2, mean_q) + masked_sq(q3, m3, mean_q))) * inv_nm1;
        float d = vp - vq;
        contrib = d * d;
    }

    // wave (64-lane) shuffle reduction
    for (int off = 32; off > 0; off >>= 1)
        contrib += __shfl_down(contrib, off, 64);

    __shared__ float partial[4];
    const int lane = threadIdx.x & 63;
    const int w = threadIdx.x >> 6;
    if (lane == 0) partial[w] = contrib;
    __syncthreads();
    if (threadIdx.x == 0) {
        float s = (partial[0] + partial[1]) + (partial[2] + partial[3]);
        atomicAdd(acc, (double)s);
    }
}

// Kernel 3: finalize scalar loss.
__global__ void rcl_final(const double* __restrict__ acc,
                          const float* __restrict__ n_multi,
                          float* __restrict__ out) {
    double nm = (double)(*n_multi);
    double total = *acc;
    double loss = (nm > 0.0) ? total / ((double)T_DIM * nm) : 0.0;
    out[0] = (float)(0.1 * loss);
}

extern "C" void kernel_launch(void* const* d_in, const int* in_sizes, int n_in,
                              void* d_out, int out_size, void* d_ws, size_t ws_size,
                              hipStream_t stream) {
    const float* pred = (const float*)d_in[0];
    const float* targ = (const float*)d_in[1];
    const float* mask = (const float*)d_in[2];
    float* out = (float*)d_out;

    double* acc = (double*)d_ws;
    float* n_multi = (float*)((char*)d_ws + 8);

    rcl_prep<<<1, B_DIM, 0, stream>>>(mask, acc, n_multi);
    rcl_main<<<(B_DIM * T_DIM) / 256, 256, 0, stream>>>(pred, targ, mask, acc);
    rcl_final<<<1, 1, 0, stream>>>(acc, n_multi, out);
}

// Round 2
// 278.348 us; speedup vs baseline: 1.0713x; 1.0713x over previous
//
#include <hip/hip_runtime.h>

#define B_DIM 512
#define T_DIM 4096
#define NSLOT 256
#define BLOCKS 8192
#define THREADS 256
#define ITER 4   // (512*4096*4 quarter-rows) / (8192*256 threads)

__device__ __forceinline__ float hsum4(float4 v) { return (v.x + v.y) + (v.z + v.w); }

__device__ __forceinline__ float mdot(float4 x, float4 m) {
    return (x.x * m.x + x.y * m.y) + (x.z * m.z + x.w * m.w);
}

__device__ __forceinline__ float msq(float4 x, float4 m, float mu) {
    float a = x.x - mu, b = x.y - mu, c = x.z - mu, d = x.w - mu;
    return (a * a * m.x + b * b * m.y) + (c * c * m.z + d * d * m.w);
}

// Main: 4 lanes per (b,t) row, one float4 each -> fully coalesced.
// Grid-stride x4 unrolled with all loads issued up front (max MLP).
__global__ __launch_bounds__(THREADS) void rcl_main(
    const float4* __restrict__ pred4, const float4* __restrict__ targ4,
    const float4* __restrict__ mask4, double* __restrict__ slots)
{
    const int tid0 = blockIdx.x * THREADS + threadIdx.x;

    float4 mv[ITER], pv[ITER], qv[ITER];
#pragma unroll
    for (int i = 0; i < ITER; i++) {
        const int g = tid0 + i * (BLOCKS * THREADS);
        const int row = g >> 2;
        const int part = g & 3;
        const int b = row >> 12;  // row / T_DIM
        mv[i] = mask4[(b << 2) + part];
        pv[i] = pred4[g];
        qv[i] = targ4[g];
    }

    float csum = 0.0f;
#pragma unroll
    for (int i = 0; i < ITER; i++) {
        // n over the 16 replicates: local quarter + 4-lane butterfly
        float n = hsum4(mv[i]);
        n += __shfl_xor(n, 1, 64);
        n += __shfl_xor(n, 2, 64);

        float sp = mdot(pv[i], mv[i]);
        sp += __shfl_xor(sp, 1, 64);
        sp += __shfl_xor(sp, 2, 64);
        float sq = mdot(qv[i], mv[i]);
        sq += __shfl_xor(sq, 1, 64);
        sq += __shfl_xor(sq, 2, 64);

        float nsafe = fmaxf(n, 2.0f);
        float mean_p = sp / nsafe;
        float mean_q = sq / nsafe;

        float vd = msq(pv[i], mv[i], mean_p) - msq(qv[i], mv[i], mean_q);
        vd += __shfl_xor(vd, 1, 64);
        vd += __shfl_xor(vd, 2, 64);

        float dd = vd / (nsafe - 1.0f);
        // all 4 lanes of the group hold identical dd -> 0.25 each; mask invalid batches
        csum += (n > 1.0f) ? dd * dd * 0.25f : 0.0f;
    }

    // wave reduce
    for (int off = 32; off > 0; off >>= 1)
        csum += __shfl_down(csum, off, 64);

    __shared__ float partial[THREADS / 64];
    const int lane = threadIdx.x & 63;
    const int w = threadIdx.x >> 6;
    if (lane == 0) partial[w] = csum;
    __syncthreads();
    if (threadIdx.x == 0) {
        float s = (partial[0] + partial[1]) + (partial[2] + partial[3]);
        atomicAdd(&slots[blockIdx.x & (NSLOT - 1)], (double)s);
    }
}

// Final: sum 256 slots + recompute n_multi from the (L2-hot) mask; write loss.
__global__ __launch_bounds__(256) void rcl_final(
    const double* __restrict__ slots, const float4* __restrict__ mask4,
    float* __restrict__ out)
{
    __shared__ double dred[256];
    __shared__ float fred[256];
    const int t = threadIdx.x;

    double tot = slots[t];

    float cnt = 0.0f;
    for (int bb = t; bb < B_DIM; bb += 256) {
        const float4* mp = mask4 + (bb << 2);
        float nn = (hsum4(mp[0]) + hsum4(mp[1])) + (hsum4(mp[2]) + hsum4(mp[3]));
        cnt += (nn > 1.0f) ? 1.0f : 0.0f;
    }

    dred[t] = tot;
    fred[t] = cnt;
    __syncthreads();
    for (int s = 128; s > 0; s >>= 1) {
        if (t < s) { dred[t] += dred[t + s]; fred[t] += fred[t + s]; }
        __syncthreads();
    }
    if (t == 0) {
        double nm = (double)fred[0];
        out[0] = (nm > 0.0) ? (float)(0.1 * (dred[0] / ((double)T_DIM * nm))) : 0.0f;
    }
}

extern "C" void kernel_launch(void* const* d_in, const int* in_sizes, int n_in,
                              void* d_out, int out_size, void* d_ws, size_t ws_size,
                              hipStream_t stream) {
    const float4* pred4 = (const float4*)d_in[0];
    const float4* targ4 = (const float4*)d_in[1];
    const float4* mask4 = (const float4*)d_in[2];
    float* out = (float*)d_out;

    double* slots = (double*)d_ws;  // NSLOT doubles

    hipMemsetAsync(d_ws, 0, NSLOT * sizeof(double), stream);
    rcl_main<<<BLOCKS, THREADS, 0, stream>>>(pred4, targ4, mask4, slots);
    rcl_final<<<1, 256, 0, stream>>>(slots, mask4, out);
}